// Round 1
// 976.693 us; speedup vs baseline: 1.0006x; 1.0006x over previous
//
#include <hip/hip_runtime.h>
#include <hip/hip_bf16.h>

#define N_NODES 50000
#define N_EDGES 800000

typedef short s16x8 __attribute__((ext_vector_type(8)));
typedef short s16x4 __attribute__((ext_vector_type(4)));
typedef float f32x4 __attribute__((ext_vector_type(4)));
typedef unsigned int u32x2 __attribute__((ext_vector_type(2)));

__device__ __forceinline__ unsigned short f2bf(float f) {
    union { float f; unsigned u; } v; v.f = f;
    unsigned r = v.u + 0x7fffu + ((v.u >> 16) & 1u);
    return (unsigned short)(r >> 16);
}

// 2x f32 -> packed bf16 pair (lo = a, hi = b). RNE, matches f2bf on normals.
__device__ __forceinline__ unsigned cvt_pk_bf16(float a, float b) {
    unsigned r;
    asm("v_cvt_pk_bf16_f32 %0, %1, %2" : "=v"(r) : "v"(a), "v"(b));
    return r;
}

__device__ __forceinline__ s16x8 ld8(const unsigned short* p) {
    return *(const s16x8*)p;
}

__device__ __forceinline__ float elu(float h) {
    return h > 0.0f ? h : (__expf(h) - 1.0f);
}

// dst[n*K + k] = bf16(src[k*N + n])   (transpose + convert)
__global__ void wconv_kernel(const float* __restrict__ src,
                             unsigned short* __restrict__ dst,
                             int K, int N) {
    int idx = blockIdx.x * 256 + threadIdx.x;
    if (idx >= K * N) return;
    int n = idx / K;
    int k = idx - n * K;
    dst[idx] = f2bf(src[k * N + n]);
}

// histogram of destination nodes (doubles as cnt)
__global__ void hist_kernel(const int* __restrict__ ei, int* __restrict__ hist) {
    int e = blockIdx.x * 256 + threadIdx.x;
    if (e < N_EDGES) atomicAdd(&hist[ei[N_EDGES + e]], 1);
}

// single-block exclusive scan of hist[50000] -> cursor[50000]
// thread-coarsened: each of 1024 threads owns 52 contiguous ints; one
// 1024-wide scan (wave shfl + 16-wave combine); ~4 barriers total instead
// of the previous 13 chunks x 20 barriers on a single CU.
__global__ void scan_kernel(const int* __restrict__ hist, int* __restrict__ cursor) {
    __shared__ int wsum[16];
    const int t = threadIdx.x;
    const int lane = t & 63, wv = t >> 6;
    const int CHUNK = 52;                 // 1024*52 = 53248 >= 50000
    const int base = t * CHUNK;

    // pass 1: per-thread chunk sum
    int s = 0;
    for (int i = 0; i < CHUNK; i += 4) {
        int idx = base + i;
        if (idx + 3 < N_NODES) {
            int4 v = *(const int4*)&hist[idx];
            s += v.x + v.y + v.z + v.w;
        } else {
#pragma unroll
            for (int j = 0; j < 4; j++)
                if (idx + j < N_NODES) s += hist[idx + j];
        }
    }
    // wave-level inclusive scan of s
    int incl = s;
#pragma unroll
    for (int off = 1; off < 64; off <<= 1) {
        int o = __shfl_up(incl, off);
        if (lane >= off) incl += o;
    }
    if (lane == 63) wsum[wv] = incl;
    __syncthreads();
    if (t == 0) {
        int c = 0;
#pragma unroll
        for (int w = 0; w < 16; w++) { int v = wsum[w]; wsum[w] = c; c += v; }
    }
    __syncthreads();
    int excl = wsum[wv] + (incl - s);   // exclusive prefix at chunk start

    // pass 2: re-read hist (L2-hot) and emit exclusive scan
    for (int i = 0; i < CHUNK; i += 4) {
        int idx = base + i;
        if (idx + 3 < N_NODES) {
            int4 v = *(const int4*)&hist[idx];
            int4 o;
            o.x = excl;
            o.y = o.x + v.x;
            o.z = o.y + v.y;
            o.w = o.z + v.z;
            *(int4*)&cursor[idx] = o;
            excl = o.w + v.w;
        } else {
#pragma unroll
            for (int j = 0; j < 4; j++)
                if (idx + j < N_NODES) { cursor[idx + j] = excl; excl += hist[idx + j]; }
        }
    }
}

// scatter edge ids into destination-sorted order
__global__ void scatter_kernel(const int* __restrict__ ei, int* __restrict__ cursor,
                               int* __restrict__ sidx) {
    int e = blockIdx.x * 256 + threadIdx.x;
    if (e >= N_EDGES) return;
    int c = ei[N_EDGES + e];
    int p = atomicAdd(&cursor[c], 1);
    sidx[p] = e;
}

#define EP 264  // edge LDS pitch in bf16 elems (256 + 8 pad)

// layer-1 of edge MLP + ELU + in-register segmented reduction + atomic scatter.
// Restructure vs previous version: segment metadata (segid per row, seg col)
// computed by wave 0 via ballot; epilogue keeps elu1 in the MFMA fragment
// registers and does per-segment masked adds + quad-fold via shfl_xor.
// Removes the bf16 LDS round-trip (128 u16 LDS ops/thread) and 2 barriers.
__global__ __launch_bounds__(256, 4) void edge_kernel(
    const float* __restrict__ x, const int* __restrict__ ei,
    const float* __restrict__ ea, const int* __restrict__ sidx,
    const float* __restrict__ b1a,
    const unsigned short* __restrict__ w1aT,
    float* __restrict__ sums)
{
    __shared__ unsigned short lA[64 * EP];
    __shared__ int lrow[64];
    __shared__ int lidx[64];
    __shared__ int lsegcol[64];
    __shared__ unsigned char lsegid[64] __attribute__((aligned(4)));
    __shared__ int lnseg;
    const int t = threadIdx.x;
    const int e0 = blockIdx.x * 64;

    if (t < 64) {  // == wave 0, fully active
        int idx = sidx[e0 + t];
        int r = ei[idx];
        int c = ei[N_EDGES + idx];
        lidx[t] = idx;
        lrow[t] = r;
        int cprev = __shfl_up(c, 1);
        int flag = (t == 0 || c != cprev) ? 1 : 0;
        unsigned long long m = __ballot(flag != 0);
        unsigned long long lm = (2ULL << t) - 1ULL;   // bits 0..t (t=63 -> ~0)
        int sid = __popcll(m & lm) - 1;
        lsegid[t] = (unsigned char)sid;
        if (flag) lsegcol[sid] = c;
        if (t == 63) lnseg = __popcll(m);
    }
    __syncthreads();

    // stage A = concat(x[row], edge_attr[idx]) as bf16 into LDS
    const f32x4* x4 = (const f32x4*)x;
    const f32x4* ea4 = (const f32x4*)ea;
#pragma unroll
    for (int i = 0; i < 8; i++) {
        int idx = i * 256 + t, r = idx >> 5, c4 = idx & 31;
        f32x4 v = x4[lrow[r] * 32 + c4];
        u32x2 b = { cvt_pk_bf16(v.x, v.y), cvt_pk_bf16(v.z, v.w) };
        *(u32x2*)&lA[r * EP + c4 * 4] = b;
    }
#pragma unroll
    for (int i = 0; i < 8; i++) {
        int idx = i * 256 + t, r = idx >> 5, c4 = idx & 31;
        f32x4 v = ea4[lidx[r] * 32 + c4];
        u32x2 b = { cvt_pk_bf16(v.x, v.y), cvt_pk_bf16(v.z, v.w) };
        *(u32x2*)&lA[r * EP + 128 + c4 * 4] = b;
    }
    __syncthreads();

    const int wv = t >> 6, lane = t & 63;
    const int quad = lane >> 4, l15 = lane & 15;

    f32x4 acc[4][4];
#pragma unroll
    for (int m = 0; m < 4; m++)
#pragma unroll
        for (int n = 0; n < 4; n++)
            acc[m][n] = (f32x4){0.f, 0.f, 0.f, 0.f};

    // layer 1: K = 256
    for (int kk = 0; kk < 8; kk++) {
        s16x8 a[4], b[4];
#pragma unroll
        for (int m = 0; m < 4; m++)
            a[m] = *(const s16x8*)&lA[(m * 16 + l15) * EP + kk * 32 + quad * 8];
#pragma unroll
        for (int n = 0; n < 4; n++)
            b[n] = ld8(&w1aT[(wv * 64 + n * 16 + l15) * 256 + kk * 32 + quad * 8]);
#pragma unroll
        for (int m = 0; m < 4; m++)
#pragma unroll
            for (int n = 0; n < 4; n++)
                acc[m][n] = __builtin_amdgcn_mfma_f32_16x16x32_bf16(a[m], b[n], acc[m][n], 0, 0, 0);
    }

    // epilogue: bias + ELU fully in registers (acc[m][n][v]: row = m*16+quad*4+v,
    // col = wv*64+n*16+l15). No LDS writeback, no further barriers.
#pragma unroll
    for (int n = 0; n < 4; n++) {
        float bias = b1a[wv * 64 + n * 16 + l15];
#pragma unroll
        for (int m = 0; m < 4; m++)
#pragma unroll
            for (int v = 0; v < 4; v++)
                acc[m][n][v] = elu(acc[m][n][v] + bias);
    }

    // in-register segmented reduction over rows (edges sorted by dest col).
    // Each thread holds rows {m*16 + quad*4 + v}; the other rows of its cols
    // live at lanes quad^1, quad^2 -> fold with shfl_xor(16), shfl_xor(32).
    unsigned gm[4];
#pragma unroll
    for (int m = 0; m < 4; m++)
        gm[m] = *(const unsigned*)&lsegid[m * 16 + quad * 4];

    const int ns = lnseg;
    const int ocol = wv * 64 + quad * 16 + l15;
    for (int s = 0; s < ns; s++) {
        float p0 = 0.f, p1 = 0.f, p2 = 0.f, p3 = 0.f;
#pragma unroll
        for (int m = 0; m < 4; m++) {
#pragma unroll
            for (int v = 0; v < 4; v++) {
                if (((gm[m] >> (8 * v)) & 255u) == (unsigned)s) {
                    p0 += acc[m][0][v];
                    p1 += acc[m][1][v];
                    p2 += acc[m][2][v];
                    p3 += acc[m][3][v];
                }
            }
        }
        p0 += __shfl_xor(p0, 16); p0 += __shfl_xor(p0, 32);
        p1 += __shfl_xor(p1, 16); p1 += __shfl_xor(p1, 32);
        p2 += __shfl_xor(p2, 16); p2 += __shfl_xor(p2, 32);
        p3 += __shfl_xor(p3, 16); p3 += __shfl_xor(p3, 32);
        float val = (quad == 0) ? p0 : (quad == 1) ? p1 : ((quad == 2) ? p2 : p3);
        atomicAdd(&sums[lsegcol[s] * 256 + ocol], val);
    }
}

#define NP 392  // node LDS pitch in bf16 elems (384 + 8 pad)

// mean_elu@w1b(+b1b) -> concat(x, mean_h) -> w2a+ELU -> w2b+b2b
__global__ __launch_bounds__(256, 3) void node_kernel(
    const float* __restrict__ x, const float* __restrict__ sums,
    const int* __restrict__ hist,
    const float* __restrict__ b1b, const float* __restrict__ b2a,
    const float* __restrict__ b2b,
    const unsigned short* __restrict__ w1bT, const unsigned short* __restrict__ w2aT,
    const unsigned short* __restrict__ w2bT,
    float* __restrict__ out)
{
    __shared__ unsigned short lZ[64 * NP];
    __shared__ float linv[64];
    __shared__ unsigned char lpos[64];
    const int t = threadIdx.x;
    const int n0 = blockIdx.x * 64;

    if (t < 64) {
        int c = 0;
        if (n0 + t < N_NODES) c = hist[n0 + t];
        lpos[t] = (c > 0);
        linv[t] = 1.0f / fmaxf((float)c, 1.0f);
    }
    __syncthreads();

    // stage x -> cols 0..128 ; mean_elu -> cols 128..384
#pragma unroll
    for (int i = 0; i < 8; i++) {
        int idx = i * 256 + t, r = idx >> 5, c4 = idx & 31;
        int node = n0 + r;
        f32x4 v = {0.f, 0.f, 0.f, 0.f};
        if (node < N_NODES) v = ((const f32x4*)x)[node * 32 + c4];
        u32x2 b = { cvt_pk_bf16(v.x, v.y), cvt_pk_bf16(v.z, v.w) };
        *(u32x2*)&lZ[r * NP + c4 * 4] = b;
    }
#pragma unroll
    for (int i = 0; i < 16; i++) {
        int idx = i * 256 + t, r = idx >> 6, c4 = idx & 63;
        int node = n0 + r;
        f32x4 v = {0.f, 0.f, 0.f, 0.f};
        if (node < N_NODES) v = ((const f32x4*)sums)[node * 64 + c4];
        float sc = linv[r];
        u32x2 b = { cvt_pk_bf16(v.x * sc, v.y * sc), cvt_pk_bf16(v.z * sc, v.w * sc) };
        *(u32x2*)&lZ[r * NP + 128 + c4 * 4] = b;
    }
    __syncthreads();

    const int wv = t >> 6, lane = t & 63;
    const int quad = lane >> 4, l15 = lane & 15;

    f32x4 acc[4][4];
#pragma unroll
    for (int m = 0; m < 4; m++)
#pragma unroll
        for (int n = 0; n < 4; n++)
            acc[m][n] = (f32x4){0.f, 0.f, 0.f, 0.f};

    // GEMM 1: mean_h = mean_elu @ w1b   (K = 256, A at col-offset 128)
    for (int kk = 0; kk < 8; kk++) {
        s16x8 a[4], b[4];
#pragma unroll
        for (int m = 0; m < 4; m++)
            a[m] = *(const s16x8*)&lZ[(m * 16 + l15) * NP + 128 + kk * 32 + quad * 8];
#pragma unroll
        for (int n = 0; n < 4; n++)
            b[n] = ld8(&w1bT[(wv * 64 + n * 16 + l15) * 256 + kk * 32 + quad * 8]);
#pragma unroll
        for (int m = 0; m < 4; m++)
#pragma unroll
            for (int n = 0; n < 4; n++)
                acc[m][n] = __builtin_amdgcn_mfma_f32_16x16x32_bf16(a[m], b[n], acc[m][n], 0, 0, 0);
    }
    __syncthreads();

    // epilogue 1: + b1b only where cnt>0 (reference gives exact 0 for isolated nodes)
#pragma unroll
    for (int m = 0; m < 4; m++)
#pragma unroll
        for (int n = 0; n < 4; n++) {
            int col = wv * 64 + n * 16 + l15;
            float bias = b1b[col];
#pragma unroll
            for (int v = 0; v < 4; v++) {
                int row = m * 16 + quad * 4 + v;
                float h = acc[m][n][v] + (lpos[row] ? bias : 0.f);
                lZ[row * NP + 128 + col] = f2bf(h);
            }
            acc[m][n] = (f32x4){0.f, 0.f, 0.f, 0.f};
        }
    __syncthreads();

    // GEMM 2: K = 384 over concat(x, mean_h)
    for (int kk = 0; kk < 12; kk++) {
        s16x8 a[4], b[4];
#pragma unroll
        for (int m = 0; m < 4; m++)
            a[m] = *(const s16x8*)&lZ[(m * 16 + l15) * NP + kk * 32 + quad * 8];
#pragma unroll
        for (int n = 0; n < 4; n++)
            b[n] = ld8(&w2aT[(wv * 64 + n * 16 + l15) * 384 + kk * 32 + quad * 8]);
#pragma unroll
        for (int m = 0; m < 4; m++)
#pragma unroll
            for (int n = 0; n < 4; n++)
                acc[m][n] = __builtin_amdgcn_mfma_f32_16x16x32_bf16(a[m], b[n], acc[m][n], 0, 0, 0);
    }
    __syncthreads();

    // epilogue 2: ELU -> H into lZ cols 0..256
#pragma unroll
    for (int m = 0; m < 4; m++)
#pragma unroll
        for (int n = 0; n < 4; n++) {
            int col = wv * 64 + n * 16 + l15;
            float bias = b2a[col];
#pragma unroll
            for (int v = 0; v < 4; v++) {
                int row = m * 16 + quad * 4 + v;
                float h = elu(acc[m][n][v] + bias);
                lZ[row * NP + col] = f2bf(h);
            }
            acc[m][n] = (f32x4){0.f, 0.f, 0.f, 0.f};
        }
    __syncthreads();

    // GEMM 3: K = 256
    for (int kk = 0; kk < 8; kk++) {
        s16x8 a[4], b[4];
#pragma unroll
        for (int m = 0; m < 4; m++)
            a[m] = *(const s16x8*)&lZ[(m * 16 + l15) * NP + kk * 32 + quad * 8];
#pragma unroll
        for (int n = 0; n < 4; n++)
            b[n] = ld8(&w2bT[(wv * 64 + n * 16 + l15) * 256 + kk * 32 + quad * 8]);
#pragma unroll
        for (int m = 0; m < 4; m++)
#pragma unroll
            for (int n = 0; n < 4; n++)
                acc[m][n] = __builtin_amdgcn_mfma_f32_16x16x32_bf16(a[m], b[n], acc[m][n], 0, 0, 0);
    }

#pragma unroll
    for (int m = 0; m < 4; m++)
#pragma unroll
        for (int n = 0; n < 4; n++) {
            int col = wv * 64 + n * 16 + l15;
            float bias = b2b[col];
#pragma unroll
            for (int v = 0; v < 4; v++) {
                int row = m * 16 + quad * 4 + v;
                int node = n0 + row;
                if (node < N_NODES)
                    out[node * 256 + col] = acc[m][n][v] + bias;
            }
        }
}

// ---- workspace layout (bytes) ----
#define WS_SUMS   0u
#define WS_HIST   51200000u
#define WS_ZERO_BYTES 51400000u   // sums + hist
#define WS_CURSOR 51400000u
#define WS_SIDX   51600000u
#define WS_W1A    54800000u
#define WS_W1B    54931072u
#define WS_W2A    55062144u
#define WS_W2B    55258752u

extern "C" void kernel_launch(void* const* d_in, const int* in_sizes, int n_in,
                              void* d_out, int out_size, void* d_ws, size_t ws_size,
                              hipStream_t stream) {
    const float* x   = (const float*)d_in[0];
    const int*   ei  = (const int*)d_in[1];
    const float* ea  = (const float*)d_in[2];
    const float* w1a = (const float*)d_in[5];
    const float* b1a = (const float*)d_in[6];
    const float* w1b = (const float*)d_in[7];
    const float* b1b = (const float*)d_in[8];
    const float* w2a = (const float*)d_in[9];
    const float* b2a = (const float*)d_in[10];
    const float* w2b = (const float*)d_in[11];
    const float* b2b = (const float*)d_in[12];
    float* out = (float*)d_out;

    char* ws = (char*)d_ws;
    float* sums = (float*)(ws + WS_SUMS);
    int* hist   = (int*)(ws + WS_HIST);
    int* cursor = (int*)(ws + WS_CURSOR);
    int* sidx   = (int*)(ws + WS_SIDX);
    unsigned short* w1aT = (unsigned short*)(ws + WS_W1A);
    unsigned short* w1bT = (unsigned short*)(ws + WS_W1B);
    unsigned short* w2aT = (unsigned short*)(ws + WS_W2A);
    unsigned short* w2bT = (unsigned short*)(ws + WS_W2B);

    hipMemsetAsync(d_ws, 0, WS_ZERO_BYTES, stream);

    wconv_kernel<<<(256 * 256 + 255) / 256, 256, 0, stream>>>(w1a, w1aT, 256, 256);
    wconv_kernel<<<(256 * 256 + 255) / 256, 256, 0, stream>>>(w1b, w1bT, 256, 256);
    wconv_kernel<<<(384 * 256 + 255) / 256, 256, 0, stream>>>(w2a, w2aT, 384, 256);
    wconv_kernel<<<(256 * 256 + 255) / 256, 256, 0, stream>>>(w2b, w2bT, 256, 256);

    hist_kernel<<<(N_EDGES + 255) / 256, 256, 0, stream>>>(ei, hist);
    scan_kernel<<<1, 1024, 0, stream>>>(hist, cursor);
    scatter_kernel<<<(N_EDGES + 255) / 256, 256, 0, stream>>>(ei, cursor, sidx);

    edge_kernel<<<N_EDGES / 64, 256, 0, stream>>>(x, ei, ea, sidx, b1a, w1aT, sums);

    node_kernel<<<(N_NODES + 63) / 64, 256, 0, stream>>>(x, sums, hist, b1b, b2a, b2b,
                                                         w1bT, w2aT, w2bT, out);
}